// Round 2
// baseline (1366.586 us; speedup 1.0000x reference)
//
#include <hip/hip_runtime.h>
#include <hip/hip_bf16.h>
#include <math.h>

#define B_   32
#define C_   684
#define H_   28
#define W_   112
#define L_   3136      // H_*W_
#define Q_   256
#define NP_  512
#define N_   256
#define K_   11
#define KK_  121       // K_*K_
#define TL   16        // l-tile per block in energy kernel

// ---------------------------------------------------------------------------
// Kernel A: hsb[b][p] = sum_n hat_s_t[b][n]*Ws[n][p] + sum_q conv_b[q]*Wf[q][p]
// grid = B_, block = 256 (each thread handles p and p+256)
// ---------------------------------------------------------------------------
__global__ __launch_bounds__(256) void k_hsb(const float* __restrict__ s,
                                             const float* __restrict__ Ws,
                                             const float* __restrict__ conv_b,
                                             const float* __restrict__ Wf,
                                             float* __restrict__ hsb) {
  int b = blockIdx.x, t = threadIdx.x;
  int p0 = t, p1 = t + 256;
  float a0 = 0.f, a1 = 0.f;
  for (int n = 0; n < N_; n++) {
    float sv = s[b * N_ + n];                 // uniform -> scalar load
    a0 += sv * Ws[n * NP_ + p0];
    a1 += sv * Ws[n * NP_ + p1];
  }
  float b0 = 0.f, b1 = 0.f;
  for (int q = 0; q < Q_; q++) {
    float cb = conv_b[q];
    b0 += cb * Wf[q * NP_ + p0];
    b1 += cb * Wf[q * NP_ + p1];
  }
  hsb[b * NP_ + p0] = a0 + b0;
  hsb[b * NP_ + p1] = a1 + b1;
}

// ---------------------------------------------------------------------------
// Kernel B: w2[kykx][p] = sum_q conv_w[q][kykx] * Wf[q][p]
// grid = 121, block = 256
// ---------------------------------------------------------------------------
__global__ __launch_bounds__(256) void k_w2(const float* __restrict__ conv_w,
                                            const float* __restrict__ Wf,
                                            float* __restrict__ w2) {
  int kk = blockIdx.x, t = threadIdx.x;
  float a0 = 0.f, a1 = 0.f;
  for (int q = 0; q < Q_; q++) {
    float cw = conv_w[q * KK_ + kk];          // uniform -> broadcast
    a0 += cw * Wf[q * NP_ + t];
    a1 += cw * Wf[q * NP_ + t + 256];
  }
  w2[kk * NP_ + t]       = a0;
  w2[kk * NP_ + t + 256] = a1;
}

// ---------------------------------------------------------------------------
// Kernel C: fused energy.
//   pre[b,l,p] = sum_c i[b,c,l]*Wa[c,p] + conv512(alpha;w2)[b,l,p] + hsb[b,p]
//   e[b,l]     = sum_p v[p]*tanh(pre[b,l,p])
// grid = (L_/TL, B_), block = 256. Thread t owns p0=t, p1=t+256 for TL l's.
// i-tile [684][16] staged in LDS (43.8 KB); alpha patch 11x26 in LDS.
// ---------------------------------------------------------------------------
__global__ __launch_bounds__(256) void k_energy(const float* __restrict__ i_,
                                                const float* __restrict__ alpha,
                                                const float* __restrict__ Wa,
                                                const float* __restrict__ w2,
                                                const float* __restrict__ hsb,
                                                const float* __restrict__ v,
                                                float* __restrict__ e_out) {
  __shared__ float shA[C_ * TL];        // [c][l] 43776 B
  __shared__ float patch[11 * 26];      // alpha halo for this l-row segment
  __shared__ float wred[TL * 4];        // cross-wave reduction

  const int b = blockIdx.y;
  const int l0 = blockIdx.x * TL;       // TL=16 divides W_=112: single y row
  const int tid = threadIdx.x;

  // stage i-tile: 684 rows x 16 floats, float4 loads
  const float* ib = i_ + (size_t)b * C_ * L_ + l0;
  for (int idx = tid; idx < C_ * 4; idx += 256) {
    int c = idx >> 2, j = idx & 3;
    float4 tv = *(const float4*)(ib + (size_t)c * L_ + j * 4);
    *(float4*)(shA + c * TL + j * 4) = tv;
  }
  // stage alpha patch (zero-padded)
  {
    int y = l0 / W_, x0 = l0 % W_;
    if (tid < 11 * 26) {
      int ry = tid / 26, cx = tid % 26;
      int yy = y - 5 + ry, xx = x0 - 5 + cx;
      float t = (yy >= 0 && yy < H_ && xx >= 0 && xx < W_)
                    ? alpha[(size_t)b * L_ + yy * W_ + xx] : 0.f;
      patch[tid] = t;
    }
  }
  __syncthreads();

  const int p0 = tid, p1 = tid + 256;
  float acc0[TL], acc1[TL];
  {
    float h0 = hsb[b * NP_ + p0], h1 = hsb[b * NP_ + p1];
#pragma unroll
    for (int l = 0; l < TL; l++) { acc0[l] = h0; acc1[l] = h1; }
  }

  // fused coverage conv (512-channel, weight-projected)
  for (int ky = 0; ky < K_; ky++) {
    float prow[26];
#pragma unroll
    for (int j = 0; j < 26; j++) prow[j] = patch[ky * 26 + j];
#pragma unroll
    for (int kx = 0; kx < K_; kx++) {
      float wa = w2[(ky * K_ + kx) * NP_ + p0];
      float wb = w2[(ky * K_ + kx) * NP_ + p1];
#pragma unroll
      for (int l = 0; l < TL; l++) {
        float t = prow[kx + l];
        acc0[l] += t * wa;
        acc1[l] += t * wb;
      }
    }
  }

  // main GEMM: sum over c of shA[c][l] * Wa[c][p]
#pragma unroll 2
  for (int c = 0; c < C_; c++) {
    float wa = Wa[(size_t)c * NP_ + p0];
    float wb = Wa[(size_t)c * NP_ + p1];
    const float4* xr = (const float4*)(shA + c * TL);
#pragma unroll
    for (int j = 0; j < 4; j++) {
      float4 xv = xr[j];
      acc0[4 * j + 0] += xv.x * wa;
      acc0[4 * j + 1] += xv.y * wa;
      acc0[4 * j + 2] += xv.z * wa;
      acc0[4 * j + 3] += xv.w * wa;
      acc1[4 * j + 0] += xv.x * wb;
      acc1[4 * j + 1] += xv.y * wb;
      acc1[4 * j + 2] += xv.z * wb;
      acc1[4 * j + 3] += xv.w * wb;
    }
  }

  // epilogue: e contribution, reduce over 512 p (256 threads x 2)
  const float v0 = v[p0], v1 = v[p1];
  float pe[TL];
#pragma unroll
  for (int l = 0; l < TL; l++)
    pe[l] = v0 * tanhf(acc0[l]) + v1 * tanhf(acc1[l]);

  const int lane = tid & 63, wv = tid >> 6;
#pragma unroll
  for (int l = 0; l < TL; l++) {
    float sv = pe[l];
    sv += __shfl_down(sv, 32);
    sv += __shfl_down(sv, 16);
    sv += __shfl_down(sv, 8);
    sv += __shfl_down(sv, 4);
    sv += __shfl_down(sv, 2);
    sv += __shfl_down(sv, 1);
    if (lane == 0) wred[l * 4 + wv] = sv;
  }
  __syncthreads();
  if (tid < TL) {
    float sv = wred[tid * 4 + 0] + wred[tid * 4 + 1] +
               wred[tid * 4 + 2] + wred[tid * 4 + 3];
    e_out[(size_t)b * L_ + l0 + tid] = sv;
  }
}

// ---------------------------------------------------------------------------
// Kernel D: softmax over L per batch. grid = B_, block = 256.
// ---------------------------------------------------------------------------
__global__ __launch_bounds__(256) void k_softmax(const float* __restrict__ e,
                                                 float* __restrict__ w) {
  __shared__ float sh[L_];
  __shared__ float red[4];
  const int b = blockIdx.x, tid = threadIdx.x;
  const int lane = tid & 63, wv = tid >> 6;

  float m = -1e30f;
  for (int idx = tid; idx < L_; idx += 256) {
    float t = e[(size_t)b * L_ + idx];
    sh[idx] = t;
    m = fmaxf(m, t);
  }
  m = fmaxf(m, __shfl_down(m, 32));
  m = fmaxf(m, __shfl_down(m, 16));
  m = fmaxf(m, __shfl_down(m, 8));
  m = fmaxf(m, __shfl_down(m, 4));
  m = fmaxf(m, __shfl_down(m, 2));
  m = fmaxf(m, __shfl_down(m, 1));
  if (lane == 0) red[wv] = m;
  __syncthreads();
  m = fmaxf(fmaxf(red[0], red[1]), fmaxf(red[2], red[3]));
  __syncthreads();

  float s = 0.f;
  for (int idx = tid; idx < L_; idx += 256) {
    float t = expf(sh[idx] - m);
    sh[idx] = t;
    s += t;
  }
  s += __shfl_down(s, 32);
  s += __shfl_down(s, 16);
  s += __shfl_down(s, 8);
  s += __shfl_down(s, 4);
  s += __shfl_down(s, 2);
  s += __shfl_down(s, 1);
  if (lane == 0) red[wv] = s;
  __syncthreads();
  float total = red[0] + red[1] + red[2] + red[3];
  float inv = 1.f / total;
  for (int idx = tid; idx < L_; idx += 256)
    w[(size_t)b * L_ + idx] = sh[idx] * inv;
}

// ---------------------------------------------------------------------------
// Kernel E: context c_At[b][c] = sum_l w[b][l] * i[b][c][l]
// grid = (C_, B_), block = 256, float4 loads (memory-bound, 275 MB read)
// ---------------------------------------------------------------------------
__global__ __launch_bounds__(256) void k_context(const float* __restrict__ i_,
                                                 const float* __restrict__ w,
                                                 float* __restrict__ out) {
  __shared__ float red[4];
  const int b = blockIdx.y, c = blockIdx.x, tid = threadIdx.x;
  const int lane = tid & 63, wv = tid >> 6;
  const float4* row = (const float4*)(i_ + ((size_t)b * C_ + c) * L_);
  const float4* wr  = (const float4*)(w + (size_t)b * L_);
  float s = 0.f;
  for (int idx = tid; idx < L_ / 4; idx += 256) {
    float4 a = row[idx];
    float4 ww = wr[idx];
    s += a.x * ww.x + a.y * ww.y + a.z * ww.z + a.w * ww.w;
  }
  s += __shfl_down(s, 32);
  s += __shfl_down(s, 16);
  s += __shfl_down(s, 8);
  s += __shfl_down(s, 4);
  s += __shfl_down(s, 2);
  s += __shfl_down(s, 1);
  if (lane == 0) red[wv] = s;
  __syncthreads();
  if (tid == 0) out[(size_t)b * C_ + c] = red[0] + red[1] + red[2] + red[3];
}

// ---------------------------------------------------------------------------
extern "C" void kernel_launch(void* const* d_in, const int* in_sizes, int n_in,
                              void* d_out, int out_size, void* d_ws, size_t ws_size,
                              hipStream_t stream) {
  const float* i_      = (const float*)d_in[0];
  const float* hat_s_t = (const float*)d_in[1];
  const float* alpha   = (const float*)d_in[2];
  const float* conv_w  = (const float*)d_in[3];
  const float* conv_b  = (const float*)d_in[4];
  const float* Wa      = (const float*)d_in[5];
  const float* Wf      = (const float*)d_in[6];
  const float* Ws      = (const float*)d_in[7];
  const float* v       = (const float*)d_in[8];
  float* out = (float*)d_out;

  float* ws   = (float*)d_ws;
  float* hsb  = ws;                               // 32*512      = 16384
  float* w2   = hsb + B_ * NP_;                   // 121*512     = 61952
  float* e    = w2 + KK_ * NP_;                   // 32*3136     = 100352
  float* anew = e + B_ * L_;                      // 32*3136     = 100352
  // total ~1.12 MB of workspace

  k_hsb<<<dim3(B_), dim3(256), 0, stream>>>(hat_s_t, Ws, conv_b, Wf, hsb);
  k_w2<<<dim3(KK_), dim3(256), 0, stream>>>(conv_w, Wf, w2);
  k_energy<<<dim3(L_ / TL, B_), dim3(256), 0, stream>>>(i_, alpha, Wa, w2, hsb, v, e);
  k_softmax<<<dim3(B_), dim3(256), 0, stream>>>(e, anew);
  k_context<<<dim3(C_, B_), dim3(256), 0, stream>>>(i_, anew, out);
}

// Round 3
// 564.295 us; speedup vs baseline: 2.4218x; 2.4218x over previous
//
#include <hip/hip_runtime.h>
#include <hip/hip_bf16.h>
#include <math.h>

#define B_   32
#define C_   684
#define H_   28
#define W_   112
#define L_   3136      // H_*W_
#define Q_   256
#define NP_  512
#define N_   256
#define K_   11
#define KK_  121       // K_*K_
#define KI_  684       // K rows from i
#define KPATCH_ 805    // 684 + 121 (im2col of alpha)
#define KT_  832       // padded K = 13*64
#define BM_  64        // l rows per block
#define KC_  64        // K chunk staged in LDS
#define NCH_ 13        // KT_/KC_

typedef short bf16x8  __attribute__((ext_vector_type(8)));
typedef short short4v __attribute__((ext_vector_type(4)));
typedef float f32x16  __attribute__((ext_vector_type(16)));

// fp32 -> bf16 round-to-nearest-even (bit trick)
__device__ __forceinline__ unsigned short f2bf(float x) {
  unsigned u = __float_as_uint(x);
  u += 0x7FFF + ((u >> 16) & 1);
  return (unsigned short)(u >> 16);
}

// ---------------------------------------------------------------------------
// Kernel A: hsb[b][p] = sum_n s[b][n]*Ws[n][p] + sum_q conv_b[q]*Wf[q][p]
// ---------------------------------------------------------------------------
__global__ __launch_bounds__(256) void k_hsb(const float* __restrict__ s,
                                             const float* __restrict__ Ws,
                                             const float* __restrict__ conv_b,
                                             const float* __restrict__ Wf,
                                             float* __restrict__ hsb) {
  int b = blockIdx.x, t = threadIdx.x;
  int p0 = t, p1 = t + 256;
  float a0 = 0.f, a1 = 0.f;
  for (int n = 0; n < N_; n++) {
    float sv = s[b * N_ + n];
    a0 += sv * Ws[n * NP_ + p0];
    a1 += sv * Ws[n * NP_ + p1];
  }
  float b0 = 0.f, b1 = 0.f;
  for (int q = 0; q < Q_; q++) {
    float cb = conv_b[q];
    b0 += cb * Wf[q * NP_ + p0];
    b1 += cb * Wf[q * NP_ + p1];
  }
  hsb[b * NP_ + p0] = a0 + b0;
  hsb[b * NP_ + p1] = a1 + b1;
}

// ---------------------------------------------------------------------------
// Kernel B: w2[kykx][p] = sum_q conv_w[q][kykx] * Wf[q][p]   (fp32)
// ---------------------------------------------------------------------------
__global__ __launch_bounds__(256) void k_w2(const float* __restrict__ conv_w,
                                            const float* __restrict__ Wf,
                                            float* __restrict__ w2) {
  int kk = blockIdx.x, t = threadIdx.x;
  float a0 = 0.f, a1 = 0.f;
  for (int q = 0; q < Q_; q++) {
    float cw = conv_w[q * KK_ + kk];
    a0 += cw * Wf[q * NP_ + t];
    a1 += cw * Wf[q * NP_ + t + 256];
  }
  w2[kk * NP_ + t]       = a0;
  w2[kk * NP_ + t + 256] = a1;
}

// ---------------------------------------------------------------------------
// Kernel B2: build Wb (bf16 hi/lo, transposed, K-padded):
//   Wb[p][k] = Wa[k][p] (k<684) | w2[k-684][p] (684<=k<805) | 0
// grid (13 k-tiles, 8 p-tiles), block 256. LDS-tiled transpose.
// ---------------------------------------------------------------------------
__global__ __launch_bounds__(256) void k_wb(const float* __restrict__ Wa,
                                            const float* __restrict__ w2,
                                            unsigned short* __restrict__ Wbh,
                                            unsigned short* __restrict__ Wbl) {
  __shared__ float tile[64][65];
  const int kt = blockIdx.x * 64, pt = blockIdx.y * 64;
  const int tid = threadIdx.x;
  for (int idx = tid; idx < 4096; idx += 256) {
    int r = idx >> 6, c = idx & 63;
    int k = kt + r, p = pt + c;
    float val = 0.f;
    if (k < KI_)          val = Wa[(size_t)k * NP_ + p];
    else if (k < KPATCH_) val = w2[(size_t)(k - KI_) * NP_ + p];
    tile[r][c] = val;
  }
  __syncthreads();
  for (int idx = tid; idx < 4096; idx += 256) {
    int pr = idx >> 6, ck = idx & 63;
    float x = tile[ck][pr];
    unsigned short hi = f2bf(x);
    float hif = __uint_as_float((unsigned)hi << 16);
    unsigned short lo = f2bf(x - hif);
    size_t o = (size_t)(pt + pr) * KT_ + kt + ck;
    Wbh[o] = hi;
    Wbl[o] = lo;
  }
}

// ---------------------------------------------------------------------------
// Kernel C: fused energy via MFMA (bf16 split, 3-term, fp32 accum).
//   pre[l][p] = sum_k A_ext[l][k]*Wb[k][p] + hsb[b][p];  A_ext = [i_T | im2col(alpha) | 0]
//   e[b][l]   = sum_p v[p]*tanh(pre[l][p])
// grid (49, 32), 512 threads = 8 waves; wave w owns p in [w*64, w*64+64),
// all 64 l rows; 2x2 tiles of v_mfma_f32_32x32x16_bf16.
// A staged in LDS (double-buffered, XOR-swizzled); B frags read from L2.
// ---------------------------------------------------------------------------
__global__ __launch_bounds__(512) void k_energy(const float* __restrict__ i_,
                                                const float* __restrict__ alpha,
                                                const unsigned short* __restrict__ Wbh,
                                                const unsigned short* __restrict__ Wbl,
                                                const float* __restrict__ hsb,
                                                const float* __restrict__ v,
                                                float* __restrict__ e_out) {
  __shared__ unsigned char As[2][2][8192];   // [buf][hi/lo][64 rows x 128 B]
  __shared__ float pe[8][64];
  const int b = blockIdx.y, l0 = blockIdx.x * BM_;
  const int tid = threadIdx.x, w = tid >> 6, lane = tid & 63;

  f32x16 acc[2][2];
#pragma unroll
  for (int mt = 0; mt < 2; mt++)
#pragma unroll
    for (int nt = 0; nt < 2; nt++)
#pragma unroll
      for (int r = 0; r < 16; r++) acc[mt][nt][r] = 0.f;

  const size_t ibase = (size_t)b * ((size_t)C_ * L_) + l0 + lane;
  const int swzw = ((lane & 7) ^ ((lane >> 3) & 7)) << 4;  // write swizzle (row = lane)

  // stage one K-chunk (64 k x 64 l) as bf16 hi/lo into As[buf]
  auto stage = [&](int buf, int ch) {
    const int kbase = ch * KC_;
#pragma unroll
    for (int s = 0; s < 2; s++) {
      const int kq = w * 8 + s * 4;          // local k-quad this thread fills
      float x[4];
      if (ch < 10) {                          // pure-i chunks: coalesced loads
#pragma unroll
        for (int q = 0; q < 4; q++)
          x[q] = i_[ibase + (size_t)(kbase + kq + q) * L_];
      } else {                                // mixed i / alpha-patch / pad
#pragma unroll
        for (int q = 0; q < 4; q++) {
          int k = kbase + kq + q;
          float t = 0.f;
          if (k < KI_) {
            t = i_[ibase + (size_t)k * L_];
          } else if (k < KPATCH_) {
            int kkp = k - KI_;
            int ky = kkp / 11, kx = kkp - ky * 11;
            int l = l0 + lane, y = l / W_, xb = l - y * W_;
            int yy = y + ky - 5, xx = xb + kx - 5;
            if (yy >= 0 && yy < H_ && xx >= 0 && xx < W_)
              t = alpha[(size_t)b * L_ + yy * W_ + xx];
          }
          x[q] = t;
        }
      }
      short4v hv, lv;
#pragma unroll
      for (int q = 0; q < 4; q++) {
        unsigned short hi = f2bf(x[q]);
        float hif = __uint_as_float((unsigned)hi << 16);
        unsigned short lo = f2bf(x[q] - hif);
        hv[q] = (short)hi;
        lv[q] = (short)lo;
      }
      const int byteoff = lane * 128 + ((kq * 2) ^ swzw);
      *(short4v*)(&As[buf][0][byteoff]) = hv;   // ds_write_b64, conflict-free
      *(short4v*)(&As[buf][1][byteoff]) = lv;
    }
  };

  stage(0, 0);
  __syncthreads();

  const int pb0 = w * 64 + (lane & 31);        // this lane's p for n-tile 0
  int buf = 0;
  for (int ch = 0; ch < NCH_; ch++) {
    if (ch + 1 < NCH_) stage(buf ^ 1, ch + 1); // prefetch next chunk into other buf
#pragma unroll
    for (int ks = 0; ks < 4; ks++) {
      const int gk = ch * KC_ + ks * 16 + ((lane >> 5) << 3);
      bf16x8 bh[2], bl[2], ah[2], al[2];
#pragma unroll
      for (int nt = 0; nt < 2; nt++) {
        const size_t bo = (size_t)(pb0 + nt * 32) * KT_ + gk;
        bh[nt] = *(const bf16x8*)(Wbh + bo);   // global dwordx4, L2-resident
        bl[nt] = *(const bf16x8*)(Wbl + bo);
      }
#pragma unroll
      for (int mt = 0; mt < 2; mt++) {
        const int row  = mt * 32 + (lane & 31);
        const int kb   = ks * 32 + ((lane >> 5) << 4);
        const int roff = row * 128 + (kb ^ (((row & 7) ^ ((row >> 3) & 7)) << 4));
        ah[mt] = *(const bf16x8*)(&As[buf][0][roff]);  // ds_read_b128
        al[mt] = *(const bf16x8*)(&As[buf][1][roff]);
      }
#pragma unroll
      for (int mt = 0; mt < 2; mt++)
#pragma unroll
        for (int nt = 0; nt < 2; nt++) {
          acc[mt][nt] = __builtin_amdgcn_mfma_f32_32x32x16_bf16(ah[mt], bh[nt], acc[mt][nt], 0, 0, 0);
          acc[mt][nt] = __builtin_amdgcn_mfma_f32_32x32x16_bf16(ah[mt], bl[nt], acc[mt][nt], 0, 0, 0);
          acc[mt][nt] = __builtin_amdgcn_mfma_f32_32x32x16_bf16(al[mt], bh[nt], acc[mt][nt], 0, 0, 0);
        }
    }
    __syncthreads();
    buf ^= 1;
  }

  // epilogue: pre = acc + hsb; partial e over this wave's 64 p
  const float h0 = hsb[b * NP_ + pb0];
  const float h1 = hsb[b * NP_ + pb0 + 32];
  const float v0 = v[pb0];
  const float v1 = v[pb0 + 32];
#pragma unroll
  for (int mt = 0; mt < 2; mt++) {
#pragma unroll
    for (int r = 0; r < 16; r++) {
      float val = v0 * tanhf(acc[mt][0][r] + h0) + v1 * tanhf(acc[mt][1][r] + h1);
      val += __shfl_xor(val, 16);
      val += __shfl_xor(val, 8);
      val += __shfl_xor(val, 4);
      val += __shfl_xor(val, 2);
      val += __shfl_xor(val, 1);
      if ((lane & 31) == 0) {
        int row = mt * 32 + (r & 3) + 8 * (r >> 2) + 4 * (lane >> 5);
        pe[w][row] = val;
      }
    }
  }
  __syncthreads();
  if (tid < BM_) {
    float s = 0.f;
#pragma unroll
    for (int ww = 0; ww < 8; ww++) s += pe[ww][tid];
    e_out[(size_t)b * L_ + l0 + tid] = s;
  }
}

// ---------------------------------------------------------------------------
// Kernel D: softmax over L per batch.
// ---------------------------------------------------------------------------
__global__ __launch_bounds__(256) void k_softmax(const float* __restrict__ e,
                                                 float* __restrict__ w) {
  __shared__ float sh[L_];
  __shared__ float red[4];
  const int b = blockIdx.x, tid = threadIdx.x;
  const int lane = tid & 63, wv = tid >> 6;

  float m = -1e30f;
  for (int idx = tid; idx < L_; idx += 256) {
    float t = e[(size_t)b * L_ + idx];
    sh[idx] = t;
    m = fmaxf(m, t);
  }
  m = fmaxf(m, __shfl_down(m, 32));
  m = fmaxf(m, __shfl_down(m, 16));
  m = fmaxf(m, __shfl_down(m, 8));
  m = fmaxf(m, __shfl_down(m, 4));
  m = fmaxf(m, __shfl_down(m, 2));
  m = fmaxf(m, __shfl_down(m, 1));
  if (lane == 0) red[wv] = m;
  __syncthreads();
  m = fmaxf(fmaxf(red[0], red[1]), fmaxf(red[2], red[3]));
  __syncthreads();

  float s = 0.f;
  for (int idx = tid; idx < L_; idx += 256) {
    float t = expf(sh[idx] - m);
    sh[idx] = t;
    s += t;
  }
  s += __shfl_down(s, 32);
  s += __shfl_down(s, 16);
  s += __shfl_down(s, 8);
  s += __shfl_down(s, 4);
  s += __shfl_down(s, 2);
  s += __shfl_down(s, 1);
  if (lane == 0) red[wv] = s;
  __syncthreads();
  float total = red[0] + red[1] + red[2] + red[3];
  float inv = 1.f / total;
  for (int idx = tid; idx < L_; idx += 256)
    w[(size_t)b * L_ + idx] = sh[idx] * inv;
}

// ---------------------------------------------------------------------------
// Kernel E: context c_At[b][c] = sum_l w[b][l] * i[b][c][l]  (memory-bound)
// ---------------------------------------------------------------------------
__global__ __launch_bounds__(256) void k_context(const float* __restrict__ i_,
                                                 const float* __restrict__ w,
                                                 float* __restrict__ out) {
  __shared__ float red[4];
  const int b = blockIdx.y, c = blockIdx.x, tid = threadIdx.x;
  const int lane = tid & 63, wv = tid >> 6;
  const float4* row = (const float4*)(i_ + ((size_t)b * C_ + c) * L_);
  const float4* wr  = (const float4*)(w + (size_t)b * L_);
  float s = 0.f;
  for (int idx = tid; idx < L_ / 4; idx += 256) {
    float4 a = row[idx];
    float4 ww = wr[idx];
    s += a.x * ww.x + a.y * ww.y + a.z * ww.z + a.w * ww.w;
  }
  s += __shfl_down(s, 32);
  s += __shfl_down(s, 16);
  s += __shfl_down(s, 8);
  s += __shfl_down(s, 4);
  s += __shfl_down(s, 2);
  s += __shfl_down(s, 1);
  if (lane == 0) red[wv] = s;
  __syncthreads();
  if (tid == 0) out[(size_t)b * C_ + c] = red[0] + red[1] + red[2] + red[3];
}

// ---------------------------------------------------------------------------
extern "C" void kernel_launch(void* const* d_in, const int* in_sizes, int n_in,
                              void* d_out, int out_size, void* d_ws, size_t ws_size,
                              hipStream_t stream) {
  const float* i_      = (const float*)d_in[0];
  const float* hat_s_t = (const float*)d_in[1];
  const float* alpha   = (const float*)d_in[2];
  const float* conv_w  = (const float*)d_in[3];
  const float* conv_b  = (const float*)d_in[4];
  const float* Wa      = (const float*)d_in[5];
  const float* Wf      = (const float*)d_in[6];
  const float* Ws      = (const float*)d_in[7];
  const float* v       = (const float*)d_in[8];
  float* out = (float*)d_out;

  float* ws   = (float*)d_ws;
  float* hsb  = ws;                               // 32*512   = 16384 f
  float* w2   = hsb + B_ * NP_;                   // 121*512  = 61952 f
  float* e    = w2 + KK_ * NP_;                   // 32*3136  = 100352 f
  float* anew = e + B_ * L_;                      // 32*3136  = 100352 f
  unsigned short* Wbh = (unsigned short*)(anew + B_ * L_);  // 512*832 u16
  unsigned short* Wbl = Wbh + (size_t)NP_ * KT_;            // 512*832 u16
  // total ~2.8 MB workspace

  k_hsb<<<dim3(B_), dim3(256), 0, stream>>>(hat_s_t, Ws, conv_b, Wf, hsb);
  k_w2<<<dim3(KK_), dim3(256), 0, stream>>>(conv_w, Wf, w2);
  k_wb<<<dim3(NCH_, 8), dim3(256), 0, stream>>>(Wa, w2, Wbh, Wbl);
  k_energy<<<dim3(L_ / BM_, B_), dim3(512), 0, stream>>>(i_, alpha, Wbh, Wbl, hsb, v, e);
  k_softmax<<<dim3(B_), dim3(256), 0, stream>>>(e, anew);
  k_context<<<dim3(C_, B_), dim3(256), 0, stream>>>(i_, anew, out);
}

// Round 4
// 549.356 us; speedup vs baseline: 2.4876x; 1.0272x over previous
//
#include <hip/hip_runtime.h>
#include <hip/hip_bf16.h>
#include <math.h>

#define B_   32
#define C_   684
#define H_   28
#define W_   112
#define L_   3136      // H_*W_
#define Q_   256
#define NP_  512
#define N_   256
#define K_   11
#define KK_  121       // K_*K_
#define KI_  684       // K rows from i
#define KPATCH_ 805    // 684 + 121 (im2col of alpha)
#define KT_  832       // padded K = 13*64
#define BM_  64        // l rows per block
#define KC_  64        // K chunk staged in LDS
#define NCH_ 13        // KT_/KC_

typedef short bf16x8  __attribute__((ext_vector_type(8)));
typedef float f32x16  __attribute__((ext_vector_type(16)));

// fp32 -> bf16 round-to-nearest-even (bit trick)
__device__ __forceinline__ unsigned short f2bf(float x) {
  unsigned u = __float_as_uint(x);
  u += 0x7FFF + ((u >> 16) & 1);
  return (unsigned short)(u >> 16);
}

// ---------------------------------------------------------------------------
// Kernel A: hsb[b][p] = sum_n s[b][n]*Ws[n][p] + sum_q conv_b[q]*Wf[q][p]
// ---------------------------------------------------------------------------
__global__ __launch_bounds__(256) void k_hsb(const float* __restrict__ s,
                                             const float* __restrict__ Ws,
                                             const float* __restrict__ conv_b,
                                             const float* __restrict__ Wf,
                                             float* __restrict__ hsb) {
  int b = blockIdx.x, t = threadIdx.x;
  int p0 = t, p1 = t + 256;
  float a0 = 0.f, a1 = 0.f;
  for (int n = 0; n < N_; n++) {
    float sv = s[b * N_ + n];
    a0 += sv * Ws[n * NP_ + p0];
    a1 += sv * Ws[n * NP_ + p1];
  }
  float b0 = 0.f, b1 = 0.f;
  for (int q = 0; q < Q_; q++) {
    float cb = conv_b[q];
    b0 += cb * Wf[q * NP_ + p0];
    b1 += cb * Wf[q * NP_ + p1];
  }
  hsb[b * NP_ + p0] = a0 + b0;
  hsb[b * NP_ + p1] = a1 + b1;
}

// ---------------------------------------------------------------------------
// Kernel B: w2[kykx][p] = sum_q conv_w[q][kykx] * Wf[q][p]   (fp32)
// ---------------------------------------------------------------------------
__global__ __launch_bounds__(256) void k_w2(const float* __restrict__ conv_w,
                                            const float* __restrict__ Wf,
                                            float* __restrict__ w2) {
  int kk = blockIdx.x, t = threadIdx.x;
  float a0 = 0.f, a1 = 0.f;
  for (int q = 0; q < Q_; q++) {
    float cw = conv_w[q * KK_ + kk];
    a0 += cw * Wf[q * NP_ + t];
    a1 += cw * Wf[q * NP_ + t + 256];
  }
  w2[kk * NP_ + t]       = a0;
  w2[kk * NP_ + t + 256] = a1;
}

// ---------------------------------------------------------------------------
// Kernel B2: build Wb (bf16 hi/lo, transposed, K-padded):
//   Wb[p][k] = Wa[k][p] (k<684) | w2[k-684][p] (684<=k<805) | 0
// ---------------------------------------------------------------------------
__global__ __launch_bounds__(256) void k_wb(const float* __restrict__ Wa,
                                            const float* __restrict__ w2,
                                            unsigned short* __restrict__ Wbh,
                                            unsigned short* __restrict__ Wbl) {
  __shared__ float tile[64][65];
  const int kt = blockIdx.x * 64, pt = blockIdx.y * 64;
  const int tid = threadIdx.x;
  for (int idx = tid; idx < 4096; idx += 256) {
    int r = idx >> 6, c = idx & 63;
    int k = kt + r, p = pt + c;
    float val = 0.f;
    if (k < KI_)          val = Wa[(size_t)k * NP_ + p];
    else if (k < KPATCH_) val = w2[(size_t)(k - KI_) * NP_ + p];
    tile[r][c] = val;
  }
  __syncthreads();
  for (int idx = tid; idx < 4096; idx += 256) {
    int pr = idx >> 6, ck = idx & 63;
    float x = tile[ck][pr];
    unsigned short hi = f2bf(x);
    float hif = __uint_as_float((unsigned)hi << 16);
    unsigned short lo = f2bf(x - hif);
    size_t o = (size_t)(pt + pr) * KT_ + kt + ck;
    Wbh[o] = hi;
    Wbl[o] = lo;
  }
}

// ---------------------------------------------------------------------------
// Kernel C: fused energy via MFMA (bf16 split, 3-term, fp32 accum).
// 256 threads = 4 waves; wave w owns p in [w*128, w*128+128) (4 nt of 32),
// all 64 l rows; 2x4 tiles of v_mfma_f32_32x32x16_bf16.
// A (i^T | im2col(alpha) | 0) converted in-kernel, staged in swizzled LDS,
// double-buffered; B (Wb hi/lo) read from global (L2-resident).
// ---------------------------------------------------------------------------
__global__ __launch_bounds__(256, 2) void k_energy(const float* __restrict__ i_,
                                                   const float* __restrict__ alpha,
                                                   const unsigned short* __restrict__ Wbh,
                                                   const unsigned short* __restrict__ Wbl,
                                                   const float* __restrict__ hsb,
                                                   const float* __restrict__ v,
                                                   float* __restrict__ e_out) {
  __shared__ unsigned char As[2][2][BM_ * 128];   // [buf][hi/lo][64 rows x 128 B] = 32 KB
  __shared__ float pe[4][BM_];

  const int b = blockIdx.y, l0 = blockIdx.x * BM_;
  const int tid = threadIdx.x, w = tid >> 6, lane = tid & 63;

  f32x16 acc[2][4];
#pragma unroll
  for (int mt = 0; mt < 2; mt++)
#pragma unroll
    for (int nt = 0; nt < 4; nt++)
#pragma unroll
      for (int r = 0; r < 16; r++) acc[mt][nt][r] = 0.f;

  // --- staging: thread owns row l = lane, k-range [w*16, w*16+16) of chunk ---
  const size_t ibase = (size_t)b * ((size_t)C_ * L_) + l0 + lane;
  const int lrow = l0 + lane;
  const int ly = lrow / W_, lx = lrow - ly * W_;

  float xs[16];
  // issue 16 coalesced global loads (256 B per wave per k)
  auto stage_load = [&](int ch) {
    const int kb = ch * KC_ + w * 16;
    if (ch < 10) {
#pragma unroll
      for (int kk = 0; kk < 16; kk++)
        xs[kk] = i_[ibase + (size_t)(kb + kk) * L_];
    } else {
#pragma unroll
      for (int kk = 0; kk < 16; kk++) {
        int k = kb + kk;
        float t = 0.f;
        if (k < KI_) {
          t = i_[ibase + (size_t)k * L_];
        } else if (k < KPATCH_) {
          int kkp = k - KI_;
          int ky = kkp / 11, kx = kkp - ky * 11;
          int yy = ly + ky - 5, xx = lx + kx - 5;
          if (yy >= 0 && yy < H_ && xx >= 0 && xx < W_)
            t = alpha[(size_t)b * L_ + yy * W_ + xx];
        }
        xs[kk] = t;
      }
    }
  };
  // convert to bf16 hi/lo and write 2 swizzled b128 per plane
  auto stage_write = [&](int buf) {
    bf16x8 hv0, hv1, lv0, lv1;
#pragma unroll
    for (int kk = 0; kk < 8; kk++) {
      unsigned short hi = f2bf(xs[kk]);
      float hif = __uint_as_float((unsigned)hi << 16);
      hv0[kk] = (short)hi;
      lv0[kk] = (short)f2bf(xs[kk] - hif);
    }
#pragma unroll
    for (int kk = 0; kk < 8; kk++) {
      unsigned short hi = f2bf(xs[8 + kk]);
      float hif = __uint_as_float((unsigned)hi << 16);
      hv1[kk] = (short)hi;
      lv1[kk] = (short)f2bf(xs[8 + kk] - hif);
    }
    const int s0 = ((w * 2 + 0) ^ (lane & 7)) * 16;
    const int s1 = ((w * 2 + 1) ^ (lane & 7)) * 16;
    *(bf16x8*)(&As[buf][0][lane * 128 + s0]) = hv0;
    *(bf16x8*)(&As[buf][0][lane * 128 + s1]) = hv1;
    *(bf16x8*)(&As[buf][1][lane * 128 + s0]) = lv0;
    *(bf16x8*)(&As[buf][1][lane * 128 + s1]) = lv1;
  };

  stage_load(0);
  stage_write(0);
  __syncthreads();

  const int pb = w * 128 + (lane & 31);       // p for nt=0
  const int kh8 = (lane >> 5) * 8;            // k-half within frag
  int buf = 0;

  for (int ch = 0; ch < NCH_; ch++) {
    if (ch + 1 < NCH_) stage_load(ch + 1);    // loads in flight under MFMA

#pragma unroll
    for (int ks = 0; ks < 4; ks++) {
      bf16x8 bh[4], bl[4];
#pragma unroll
      for (int nt = 0; nt < 4; nt++) {
        const size_t bo = (size_t)(pb + nt * 32) * KT_ + ch * KC_ + ks * 16 + kh8;
        bh[nt] = *(const bf16x8*)(Wbh + bo);
        bl[nt] = *(const bf16x8*)(Wbl + bo);
      }
      bf16x8 ah[2], al[2];
#pragma unroll
      for (int mt = 0; mt < 2; mt++) {
        const int row = mt * 32 + (lane & 31);
        const int off = row * 128 + (((ks * 2 + (lane >> 5)) ^ (row & 7)) * 16);
        ah[mt] = *(const bf16x8*)(&As[buf][0][off]);
        al[mt] = *(const bf16x8*)(&As[buf][1][off]);
      }
#pragma unroll
      for (int mt = 0; mt < 2; mt++)
#pragma unroll
        for (int nt = 0; nt < 4; nt++) {
          acc[mt][nt] = __builtin_amdgcn_mfma_f32_32x32x16_bf16(ah[mt], bh[nt], acc[mt][nt], 0, 0, 0);
          acc[mt][nt] = __builtin_amdgcn_mfma_f32_32x32x16_bf16(ah[mt], bl[nt], acc[mt][nt], 0, 0, 0);
          acc[mt][nt] = __builtin_amdgcn_mfma_f32_32x32x16_bf16(al[mt], bh[nt], acc[mt][nt], 0, 0, 0);
        }
    }

    if (ch + 1 < NCH_) {
      stage_write(buf ^ 1);                   // convert + LDS write after MFMA
      __syncthreads();
      buf ^= 1;
    }
  }

  // epilogue: pre = acc + hsb; e partial over this wave's 128 p
  float hv[4], vv[4];
#pragma unroll
  for (int nt = 0; nt < 4; nt++) {
    hv[nt] = hsb[b * NP_ + pb + nt * 32];
    vv[nt] = v[pb + nt * 32];
  }
#pragma unroll
  for (int mt = 0; mt < 2; mt++) {
#pragma unroll
    for (int r = 0; r < 16; r++) {
      float val = 0.f;
#pragma unroll
      for (int nt = 0; nt < 4; nt++)
        val += vv[nt] * tanhf(acc[mt][nt][r] + hv[nt]);
      val += __shfl_xor(val, 16);
      val += __shfl_xor(val, 8);
      val += __shfl_xor(val, 4);
      val += __shfl_xor(val, 2);
      val += __shfl_xor(val, 1);
      if ((lane & 31) == 0) {
        int row = mt * 32 + (r & 3) + 8 * (r >> 2) + 4 * (lane >> 5);
        pe[w][row] = val;
      }
    }
  }
  __syncthreads();
  if (tid < BM_) {
    float s = pe[0][tid] + pe[1][tid] + pe[2][tid] + pe[3][tid];
    e_out[(size_t)b * L_ + l0 + tid] = s;
  }
}

// ---------------------------------------------------------------------------
// Kernel D: softmax over L per batch.
// ---------------------------------------------------------------------------
__global__ __launch_bounds__(256) void k_softmax(const float* __restrict__ e,
                                                 float* __restrict__ w) {
  __shared__ float sh[L_];
  __shared__ float red[4];
  const int b = blockIdx.x, tid = threadIdx.x;
  const int lane = tid & 63, wv = tid >> 6;

  float m = -1e30f;
  for (int idx = tid; idx < L_; idx += 256) {
    float t = e[(size_t)b * L_ + idx];
    sh[idx] = t;
    m = fmaxf(m, t);
  }
  m = fmaxf(m, __shfl_down(m, 32));
  m = fmaxf(m, __shfl_down(m, 16));
  m = fmaxf(m, __shfl_down(m, 8));
  m = fmaxf(m, __shfl_down(m, 4));
  m = fmaxf(m, __shfl_down(m, 2));
  m = fmaxf(m, __shfl_down(m, 1));
  if (lane == 0) red[wv] = m;
  __syncthreads();
  m = fmaxf(fmaxf(red[0], red[1]), fmaxf(red[2], red[3]));
  __syncthreads();

  float s = 0.f;
  for (int idx = tid; idx < L_; idx += 256) {
    float t = expf(sh[idx] - m);
    sh[idx] = t;
    s += t;
  }
  s += __shfl_down(s, 32);
  s += __shfl_down(s, 16);
  s += __shfl_down(s, 8);
  s += __shfl_down(s, 4);
  s += __shfl_down(s, 2);
  s += __shfl_down(s, 1);
  if (lane == 0) red[wv] = s;
  __syncthreads();
  float total = red[0] + red[1] + red[2] + red[3];
  float inv = 1.f / total;
  for (int idx = tid; idx < L_; idx += 256)
    w[(size_t)b * L_ + idx] = sh[idx] * inv;
}

// ---------------------------------------------------------------------------
// Kernel E: context c_At[b][c] = sum_l w[b][l] * i[b][c][l]  (memory-bound)
// ---------------------------------------------------------------------------
__global__ __launch_bounds__(256) void k_context(const float* __restrict__ i_,
                                                 const float* __restrict__ w,
                                                 float* __restrict__ out) {
  __shared__ float red[4];
  const int b = blockIdx.y, c = blockIdx.x, tid = threadIdx.x;
  const int lane = tid & 63, wv = tid >> 6;
  const float4* row = (const float4*)(i_ + ((size_t)b * C_ + c) * L_);
  const float4* wr  = (const float4*)(w + (size_t)b * L_);
  float s = 0.f;
  for (int idx = tid; idx < L_ / 4; idx += 256) {
    float4 a = row[idx];
    float4 ww = wr[idx];
    s += a.x * ww.x + a.y * ww.y + a.z * ww.z + a.w * ww.w;
  }
  s += __shfl_down(s, 32);
  s += __shfl_down(s, 16);
  s += __shfl_down(s, 8);
  s += __shfl_down(s, 4);
  s += __shfl_down(s, 2);
  s += __shfl_down(s, 1);
  if (lane == 0) red[wv] = s;
  __syncthreads();
  if (tid == 0) out[(size_t)b * C_ + c] = red[0] + red[1] + red[2] + red[3];
}

// ---------------------------------------------------------------------------
extern "C" void kernel_launch(void* const* d_in, const int* in_sizes, int n_in,
                              void* d_out, int out_size, void* d_ws, size_t ws_size,
                              hipStream_t stream) {
  const float* i_      = (const float*)d_in[0];
  const float* hat_s_t = (const float*)d_in[1];
  const float* alpha   = (const float*)d_in[2];
  const float* conv_w  = (const float*)d_in[3];
  const float* conv_b  = (const float*)d_in[4];
  const float* Wa      = (const float*)d_in[5];
  const float* Wf      = (const float*)d_in[6];
  const float* Ws      = (const float*)d_in[7];
  const float* v       = (const float*)d_in[8];
  float* out = (float*)d_out;

  float* ws   = (float*)d_ws;
  float* hsb  = ws;                               // 32*512   = 16384 f
  float* w2   = hsb + B_ * NP_;                   // 121*512  = 61952 f
  float* e    = w2 + KK_ * NP_;                   // 32*3136  = 100352 f
  float* anew = e + B_ * L_;                      // 32*3136  = 100352 f
  unsigned short* Wbh = (unsigned short*)(anew + B_ * L_);  // 512*832 u16
  unsigned short* Wbl = Wbh + (size_t)NP_ * KT_;            // 512*832 u16
  // total ~2.8 MB workspace

  k_hsb<<<dim3(B_), dim3(256), 0, stream>>>(hat_s_t, Ws, conv_b, Wf, hsb);
  k_w2<<<dim3(KK_), dim3(256), 0, stream>>>(conv_w, Wf, w2);
  k_wb<<<dim3(NCH_, 8), dim3(256), 0, stream>>>(Wa, w2, Wbh, Wbl);
  k_energy<<<dim3(L_ / BM_, B_), dim3(256), 0, stream>>>(i_, alpha, Wbh, Wbl, hsb, v, e);
  k_softmax<<<dim3(B_), dim3(256), 0, stream>>>(e, anew);
  k_context<<<dim3(C_, B_), dim3(256), 0, stream>>>(i_, anew, out);
}